// Round 2
// baseline (4675.235 us; speedup 1.0000x reference)
//
#include <hip/hip_runtime.h>
#include <math.h>

#define SEQ 400
#define HD  1024
#define VV  50000
#define VP  50050
#define NINF -1e12f

// ---------------- helpers ----------------
__device__ __forceinline__ void atomicMaxF(float* addr, float v){
  v = v + 0.0f;                       // canonicalize -0.0 -> +0.0
  if (v >= 0.0f) atomicMax((int*)addr, __float_as_int(v));
  else           atomicMin((unsigned int*)addr, __float_as_uint(v));
}

__global__ void fill_ninf(float4* __restrict__ p, int n4){
  int i = blockIdx.x*blockDim.x + threadIdx.x;
  if (i < n4) p[i] = make_float4(NINF, NINF, NINF, NINF);
}

// (weighted) sum over S chunks: partial[b][c][h], 8 chunks of 50
__global__ void wsum_partial(const float* __restrict__ enc, const float* __restrict__ wts,
                             float* __restrict__ partial){
  int b = blockIdx.x >> 3, c = blockIdx.x & 7;
  int t = threadIdx.x;
  const float* p  = enc + ((size_t)b*SEQ + c*50)*HD;
  const float* wp = wts ? (wts + b*SEQ + c*50) : nullptr;
  float a0=0.f,a1=0.f,a2=0.f,a3=0.f;
  for (int s=0; s<50; ++s){
    float w = wp ? wp[s] : 1.0f;
    const float* r = p + (size_t)s*HD;
    a0 += w*r[t]; a1 += w*r[t+256]; a2 += w*r[t+512]; a3 += w*r[t+768];
  }
  float* o = partial + (size_t)(b*8+c)*HD;
  o[t]=a0; o[t+256]=a1; o[t+512]=a2; o[t+768]=a3;
}

__global__ void wsum_reduce(const float* __restrict__ partial, float* __restrict__ outv, float scale){
  int i = blockIdx.x*blockDim.x + threadIdx.x;   // over 64*HD
  int b = i >> 10, h = i & 1023;
  float s = 0.f;
  #pragma unroll
  for (int c=0; c<8; ++c) s += partial[(size_t)(b*8+c)*HD + h];
  outv[i] = s*scale;
}

__global__ void transpose1024(const float* __restrict__ in, float* __restrict__ out){
  __shared__ float tile[32][33];
  int x  = blockIdx.x*32 + threadIdx.x;
  int y0 = blockIdx.y*32;
  for (int j=threadIdx.y; j<32; j+=8) tile[j][threadIdx.x] = in[(size_t)(y0+j)*HD + x];
  __syncthreads();
  int xo = blockIdx.y*32 + threadIdx.x;
  int yo = blockIdx.x*32;
  for (int j=threadIdx.y; j<32; j+=8) out[(size_t)(yo+j)*HD + xo] = tile[threadIdx.x][j];
}

// ---------------- skinny GEMM: out[64][N] = concat(inA,inB,inC) @ [WA;WB;WC] + bias ----------------
// thread owns 4 batch rows (bg=t>>4) x 8 cols (nt=t&15). in-tile staged k-major in LDS.
// mode 0: plain, 1: tanh, 2: logit epilogue (merge scat staged in out, UNK col, ldo=VP)
#define TK 32
__global__ __launch_bounds__(256) void gemm64(
    const float* __restrict__ inA, const float* __restrict__ WA, int KA, const int* __restrict__ gA,
    const float* __restrict__ inB, const float* __restrict__ WB, int KB,
    const float* __restrict__ inC, const float* __restrict__ WC, int KC,
    const float* __restrict__ bias1, const float* __restrict__ bias2,
    float* __restrict__ out, float* __restrict__ out2,
    int N, int ldo, int mode){
  __shared__ float lds[TK*68];
  int t  = threadIdx.x;
  int bg = t >> 4;            // 0..15 -> rows bg*4..bg*4+3
  int nt = t & 15;
  int n0 = (blockIdx.x*16 + nt)*8;
  bool nact = n0 < N;
  bool nvec = (n0 + 8) <= N;
  int KT = KA + KB + KC;
  float acc[4][8] = {};
  for (int k0 = 0; k0 < KT; k0 += TK){
    #pragma unroll
    for (int i=0; i<8; ++i){                 // stage 64 x 32 in-tile
      int idx = i*256 + t;
      int bb = idx >> 5, kk = idx & 31;
      int kg = k0 + kk;
      float v = 0.0f;
      if (kg < KT){
        if (kg < KA){
          int row = gA ? gA[bb] : bb;
          v = inA[(size_t)row*KA + kg];
        } else if (kg < KA+KB){
          v = inB[(size_t)bb*KB + (kg-KA)];
        } else {
          v = inC[(size_t)bb*KC + (kg-KA-KB)];
        }
      }
      lds[kk*68 + bb] = v;
    }
    __syncthreads();
    #pragma unroll
    for (int kk=0; kk<TK; ++kk){
      int kg = k0 + kk;
      float w[8];
      if (nact && kg < KT){
        const float* wp;
        if (kg < KA)          wp = WA + (size_t)kg*N;
        else if (kg < KA+KB)  wp = WB + (size_t)(kg-KA)*N;
        else                  wp = WC + (size_t)(kg-KA-KB)*N;
        if (nvec){
          float4 w0 = *(const float4*)(wp + n0);
          float4 w1 = *(const float4*)(wp + n0 + 4);
          w[0]=w0.x; w[1]=w0.y; w[2]=w0.z; w[3]=w0.w;
          w[4]=w1.x; w[5]=w1.y; w[6]=w1.z; w[7]=w1.w;
        } else {
          #pragma unroll
          for (int j=0; j<8; ++j) w[j] = (n0+j < N) ? wp[n0+j] : 0.0f;
        }
      } else {
        #pragma unroll
        for (int j=0; j<8; ++j) w[j] = 0.0f;
      }
      float4 av = *(const float4*)(lds + kk*68 + bg*4);
      float a4[4] = {av.x, av.y, av.z, av.w};
      #pragma unroll
      for (int bi=0; bi<4; ++bi)
        #pragma unroll
        for (int j=0; j<8; ++j)
          acc[bi][j] += a4[bi]*w[j];
    }
    __syncthreads();
  }
  if (!nact) return;
  int b0 = bg*4;
  #pragma unroll
  for (int j=0; j<8; ++j){
    int n = n0 + j;
    if (n < N){
      float bv = (bias1 ? bias1[n] : 0.0f) + (bias2 ? bias2[n] : 0.0f);
      #pragma unroll
      for (int bi=0; bi<4; ++bi){
        float v = acc[bi][j] + bv;
        if (mode == 1) v = tanhf(v);
        size_t o = (size_t)(b0+bi)*ldo + n;
        if (mode == 2){
          float sc = out[o];                 // scat staged by scatter_kernel
          v += (sc == NINF) ? 0.0f : sc;
          if (n == 1) v = NINF;              // UNK_ID
        }
        out[o] = v;
        if (out2) out2[(size_t)(b0+bi)*N + n] = v;
      }
    }
  }
}

// ---------------- LSTM cell + h.b_enc dot ----------------
__global__ __launch_bounds__(1024) void lstm_kernel(
    const float* __restrict__ gates, const float* __restrict__ prev_c,
    const float* __restrict__ b_enc,
    float* __restrict__ hbuf, float* __restrict__ hb,
    float* __restrict__ out_h, float* __restrict__ out_c){
  int b = blockIdx.x, h = threadIdx.x;
  size_t g0 = (size_t)b*4096;
  float ig = gates[g0+h], fg = gates[g0+1024+h], gg = gates[g0+2048+h], og = gates[g0+3072+h];
  float c0 = prev_c[(size_t)b*HD + h];
  float si = 1.0f/(1.0f+expf(-ig));
  float sf = 1.0f/(1.0f+expf(-fg));
  float so = 1.0f/(1.0f+expf(-og));
  float c  = sf*c0 + si*tanhf(gg);
  float hv = so*tanhf(c);
  size_t o = (size_t)b*HD + h;
  hbuf[o]=hv; out_h[o]=hv; out_c[o]=c;
  float p = hv * b_enc[h];
  #pragma unroll
  for (int off=32; off; off>>=1) p += __shfl_xor(p, off, 64);
  __shared__ float red[16];
  if ((h & 63) == 0) red[h>>6] = p;
  __syncthreads();
  if (h == 0){
    float s = 0.f;
    #pragma unroll
    for (int i=0; i<16; ++i) s += red[i];
    hb[b] = s;
  }
}

// energy[b,s] = hW[b].enc[b,s] + hb[b], masked
__global__ void energy_kernel(const float* __restrict__ hW, const float* __restrict__ enc,
                              const float* __restrict__ hb, const int* __restrict__ mask,
                              float* __restrict__ energy){
  int b  = blockIdx.x / 100;
  int s0 = (blockIdx.x % 100)*4;
  __shared__ float sh[HD];
  for (int i=threadIdx.x; i<HD; i+=256) sh[i] = hW[(size_t)b*HD + i];
  __syncthreads();
  int wid = threadIdx.x >> 6, l = threadIdx.x & 63;
  int s = s0 + wid;
  const float* ep = enc + ((size_t)b*SEQ + s)*HD;
  float d = 0.f;
  #pragma unroll
  for (int it=0; it<4; ++it){
    int hh = it*256 + l*4;
    float4 e = *(const float4*)(ep + hh);
    float4 a = *(const float4*)(sh + hh);
    d += a.x*e.x + a.y*e.y + a.z*e.z + a.w*e.w;
  }
  #pragma unroll
  for (int off=32; off; off>>=1) d += __shfl_xor(d, off, 64);
  if (l == 0){
    float v = d + hb[b];
    if (mask[b*SEQ + s]) v = NINF;
    energy[b*SEQ + s] = v;
  }
}

__global__ void softmax_kernel(const float* __restrict__ energy, float* __restrict__ attn){
  int b = blockIdx.x, t = threadIdx.x;      // 256 threads, S=400
  __shared__ float red[256];
  float e0 = energy[b*SEQ + t];
  float e1 = (t+256 < SEQ) ? energy[b*SEQ + t + 256] : NINF;
  red[t] = fmaxf(e0, e1);
  __syncthreads();
  for (int o=128; o; o>>=1){ if (t < o) red[t] = fmaxf(red[t], red[t+o]); __syncthreads(); }
  float m = red[0];
  __syncthreads();
  float x0 = expf(e0 - m);
  float x1 = (t+256 < SEQ) ? expf(e1 - m) : 0.0f;
  red[t] = x0 + x1;
  __syncthreads();
  for (int o=128; o; o>>=1){ if (t < o) red[t] += red[t+o]; __syncthreads(); }
  float inv = 1.0f / red[0];
  attn[b*SEQ + t] = x0*inv;
  if (t+256 < SEQ) attn[b*SEQ + t + 256] = x1*inv;
}

__global__ void scatter_kernel(const float* __restrict__ energy, const int* __restrict__ ext_x,
                               float* __restrict__ out){
  int i = blockIdx.x*blockDim.x + threadIdx.x;
  if (i >= 64*SEQ) return;
  int b = i / SEQ;
  atomicMaxF(out + (size_t)b*VP + ext_x[i], energy[i]);
}

__global__ void oov_kernel(float* __restrict__ out){
  int i = blockIdx.x*blockDim.x + threadIdx.x;
  if (i >= 64*50) return;
  int b = i/50, j = i%50;
  size_t o = (size_t)b*VP + VV + j;
  float s = out[o];
  out[o] = (s == NINF) ? 0.0f : s;
}

// ---------------- launch ----------------
extern "C" void kernel_launch(void* const* d_in, const int* in_sizes, int n_in,
                              void* d_out, int out_size, void* d_ws, size_t ws_size,
                              hipStream_t stream){
  const int*   y       = (const int*)d_in[0];
  const int*   ext_x   = (const int*)d_in[1];
  const float* prev_h  = (const float*)d_in[2];   // (1,B,H)
  const float* prev_c  = (const float*)d_in[3];
  const float* prev_ctx= (const float*)d_in[4];   // (B,1,H)
  const float* enc     = (const float*)d_in[5];   // (B,S,H)
  const int*   mask    = (const int*)d_in[6];     // bool -> int32
  const float* decout  = (const float*)d_in[7];   // (B,1,E)
  const float* emb     = (const float*)d_in[8];
  const float* W_enc   = (const float*)d_in[9];
  const float* b_enc   = (const float*)d_in[10];
  const float* W_comb  = (const float*)d_in[11];
  const float* b_comb  = (const float*)d_in[12];
  const float* W_red   = (const float*)d_in[13];
  const float* b_red   = (const float*)d_in[14];
  const float* W_ih    = (const float*)d_in[15];
  const float* W_hh    = (const float*)d_in[16];
  const float* b_ih    = (const float*)d_in[17];
  const float* b_hh    = (const float*)d_in[18];
  const float* W_cat   = (const float*)d_in[19];
  const float* b_cat   = (const float*)d_in[20];
  const float* W_logit = (const float*)d_in[21];
  const float* b_logit = (const float*)d_in[22];

  float* ws      = (float*)d_ws;
  float* partial = ws;                 // 524288
  float* pooled  = ws + 524288;        // 65536
  float* encpool = ws + 589824;        // 65536
  float* combined= ws + 655360;        // 19200
  float* xbuf    = ws + 674560;        // 19200
  float* gates   = ws + 693760;        // 262144
  float* hbuf    = ws + 955904;        // 65536
  float* hb      = ws + 1021440;       // 64
  float* WencT   = ws + 1021504;       // 1048576
  float* hWb     = ws + 2070080;       // 65536
  float* energy  = ws + 2135616;       // 25600
  float* attn    = ws + 2161216;       // 25600
  float* ctxraw  = ws + 2186816;       // 65536
  float* ctxbuf  = ws + 2252352;       // 65536
  float* logitin = ws + 2317888;       // 65536

  float* out     = (float*)d_out;
  float* out_h   = out + 3203200;
  float* out_c   = out_h + 65536;
  float* out_ctx = out_c + 65536;

  // scat staging: logit region := -INF
  fill_ninf<<<3129,256,0,stream>>>((float4*)out, 800800);
  // pooled encoder mean (pre-W_enc)
  wsum_partial<<<512,256,0,stream>>>(enc, nullptr, partial);
  wsum_reduce<<<256,256,0,stream>>>(partial, pooled, 1.0f/SEQ);
  transpose1024<<<dim3(32,32),dim3(32,8),0,stream>>>(W_enc, WencT);
  // enc_pooled = pooled @ W_enc + b_enc
  gemm64<<<8,256,0,stream>>>(pooled, W_enc, 1024, nullptr, nullptr,nullptr,0,
                             nullptr,nullptr,0, b_enc,nullptr, encpool,nullptr, 1024,1024,0);
  // combined = [emb[y], enc_pooled, decoder_out] @ W_comb + b_comb
  gemm64<<<3,256,0,stream>>>(emb, W_comb, 300, y, encpool, W_comb+300*300, 1024,
                             decout, W_comb+1324*300, 300, b_comb,nullptr, combined,nullptr, 300,300,0);
  // x = [combined, prev_context] @ W_red + b_red
  gemm64<<<3,256,0,stream>>>(combined, W_red, 300, nullptr, prev_ctx, W_red+300*300, 1024,
                             nullptr,nullptr,0, b_red,nullptr, xbuf,nullptr, 300,300,0);
  // gates = x@W_ih + h0@W_hh + b_ih + b_hh
  gemm64<<<32,256,0,stream>>>(xbuf, W_ih, 300, nullptr, prev_h, W_hh, 1024,
                              nullptr,nullptr,0, b_ih,b_hh, gates,nullptr, 4096,4096,0);
  lstm_kernel<<<64,1024,0,stream>>>(gates, prev_c, b_enc, hbuf, hb, out_h, out_c);
  // hW = h @ W_enc^T
  gemm64<<<8,256,0,stream>>>(hbuf, WencT, 1024, nullptr, nullptr,nullptr,0,
                             nullptr,nullptr,0, nullptr,nullptr, hWb,nullptr, 1024,1024,0);
  energy_kernel<<<6400,256,0,stream>>>(hWb, enc, hb, mask, energy);
  softmax_kernel<<<64,256,0,stream>>>(energy, attn);
  scatter_kernel<<<100,256,0,stream>>>(energy, ext_x, out);
  oov_kernel<<<13,256,0,stream>>>(out);
  // context = (attn-weighted enc sum) @ W_enc + b_enc
  wsum_partial<<<512,256,0,stream>>>(enc, attn, partial);
  wsum_reduce<<<256,256,0,stream>>>(partial, ctxraw, 1.0f);
  gemm64<<<8,256,0,stream>>>(ctxraw, W_enc, 1024, nullptr, nullptr,nullptr,0,
                             nullptr,nullptr,0, b_enc,nullptr, ctxbuf,out_ctx, 1024,1024,0);
  // logit_in = tanh([h, context] @ W_cat + b_cat)
  gemm64<<<8,256,0,stream>>>(hbuf, W_cat, 1024, nullptr, ctxbuf, W_cat+1024*1024, 1024,
                             nullptr,nullptr,0, b_cat,nullptr, logitin,nullptr, 1024,1024,1);
  // out_logit = logit_in @ W_logit + b_logit (+scat merge, UNK)
  gemm64<<<391,256,0,stream>>>(logitin, W_logit, 1024, nullptr, nullptr,nullptr,0,
                               nullptr,nullptr,0, b_logit,nullptr, out,nullptr, 50000,50050,2);
}

// Round 11
// 1694.128 us; speedup vs baseline: 2.7597x; 2.7597x over previous
//
#include <hip/hip_runtime.h>
#include <math.h>

#define SEQ 400
#define HD  1024
#define VV  50000
#define VP  50050
#define NINF -1e12f

// ---------------- helpers ----------------
__device__ __forceinline__ void atomicMaxF(float* addr, float v){
  v = v + 0.0f;                       // canonicalize -0.0 -> +0.0
  if (v >= 0.0f) atomicMax((int*)addr, __float_as_int(v));
  else           atomicMin((unsigned int*)addr, __float_as_uint(v));
}

__device__ __forceinline__ void f4fma(float4& a, const float4& w, float s){
  a.x = fmaf(w.x, s, a.x); a.y = fmaf(w.y, s, a.y);
  a.z = fmaf(w.z, s, a.z); a.w = fmaf(w.w, s, a.w);
}

__device__ __forceinline__ void fma16(float4 acc[16], const float4 w, const float4 xa[4]){
  #pragma unroll
  for (int j = 0; j < 4; ++j){
    float4 xv = xa[j];
    f4fma(acc[j*4+0], w, xv.x);
    f4fma(acc[j*4+1], w, xv.y);
    f4fma(acc[j*4+2], w, xv.z);
    f4fma(acc[j*4+3], w, xv.w);
  }
}

__global__ void fill_ninf(float4* __restrict__ p, int n4){
  int i = blockIdx.x*blockDim.x + threadIdx.x;
  if (i < n4) p[i] = make_float4(NINF, NINF, NINF, NINF);
}

// (weighted) sum over S chunks: partial[b][c][h], 8 chunks of 50
__global__ void wsum_partial(const float* __restrict__ enc, const float* __restrict__ wts,
                             float* __restrict__ partial){
  int b = blockIdx.x >> 3, c = blockIdx.x & 7;
  int t = threadIdx.x;
  const float* p  = enc + ((size_t)b*SEQ + c*50)*HD;
  const float* wp = wts ? (wts + b*SEQ + c*50) : nullptr;
  float a0=0.f,a1=0.f,a2=0.f,a3=0.f;
  for (int s=0; s<50; ++s){
    float w = wp ? wp[s] : 1.0f;
    const float* r = p + (size_t)s*HD;
    a0 += w*r[t]; a1 += w*r[t+256]; a2 += w*r[t+512]; a3 += w*r[t+768];
  }
  float* o = partial + (size_t)(b*8+c)*HD;
  o[t]=a0; o[t+256]=a1; o[t+512]=a2; o[t+768]=a3;
}

// reduce 8 chunks; transposed=1 writes outv[h*64+b] (k-major for gemm_v2)
__global__ void wsum_reduce(const float* __restrict__ partial, float* __restrict__ outv,
                            float scale, int transposed){
  int i = blockIdx.x*blockDim.x + threadIdx.x;   // over 64*HD
  int b = i >> 10, h = i & 1023;
  float s = 0.f;
  #pragma unroll
  for (int c=0; c<8; ++c) s += partial[(size_t)(b*8+c)*HD + h];
  s *= scale;
  if (transposed) outv[(size_t)h*64 + b] = s;
  else            outv[(size_t)b*HD + h] = s;
}

__global__ void transpose1024(const float* __restrict__ in, float* __restrict__ out){
  __shared__ float tile[32][33];
  int x  = blockIdx.x*32 + threadIdx.x;
  int y0 = blockIdx.y*32;
  for (int j=threadIdx.y; j<32; j+=8) tile[j][threadIdx.x] = in[(size_t)(y0+j)*HD + x];
  __syncthreads();
  int xo = blockIdx.y*32 + threadIdx.x;
  int yo = blockIdx.x*32;
  for (int j=threadIdx.y; j<32; j+=8) out[(size_t)(yo+j)*HD + xo] = tile[threadIdx.x][j];
}

// build k-major xT[k][b] from row-major src[64][K] (optional row gather)
__global__ void build_xt(const float* __restrict__ src, int K, const int* __restrict__ g,
                         float* __restrict__ dst){
  int b = threadIdx.x;                // 0..63
  int k = blockIdx.x*4 + threadIdx.y; // block (64,4)
  if (k >= K) return;
  int row = g ? g[b] : b;
  dst[(size_t)k*64 + b] = src[(size_t)row*K + k];
}

// ---------------- streaming skinny GEMM v2 ----------------
// out[64][N] (+=split over blockIdx.y) = xT^T @ W.  xT is k-major [K][64].
// thread: 16 b-rows x 4 cols. 128 threads: bg=t>>5 (4 groups x 16b), nt=t&31 (128 cols/blk).
// per k: 1 coalesced float4 W load + 4 broadcast float4 x loads + 64 FMA. depth-2 prefetch.
// mode 0: write partial[(ky_base+ky)*64+b][n] (bias in reduce)
// mode 2: logit epilogue direct to out (ldo=VP): +bias, merge scat staged in out, UNK col
__global__ __launch_bounds__(128) void gemm_v2(
    const float* __restrict__ xT, const float* __restrict__ W,
    const float* __restrict__ bias,
    float* __restrict__ outp, int K, int N, int kchunk, int ky_base, int mode){
  int t  = threadIdx.x;
  int bg = t >> 5;                 // 0..3 -> b0 = bg*16
  int nt = t & 31;
  int n0 = blockIdx.x*128 + nt*4;
  bool nact = n0 < N;
  int nq  = nact ? (n0 >> 2) : 0;  // safe col for loads
  int bg4 = bg << 2;
  int kb = blockIdx.y * kchunk;
  int ke = kb + kchunk; if (ke > K) ke = K;   // kchunk even, K even -> (ke-kb) even

  float4 acc[16];
  #pragma unroll
  for (int i=0;i<16;++i) acc[i] = make_float4(0.f,0.f,0.f,0.f);

  float4 w0, w1, x0[4], x1[4];
  {
    const float4* wr0 = (const float4*)(W + (size_t)kb*N) + nq;       w0 = *wr0;
    const float4* xr0 = (const float4*)(xT + ((size_t)kb<<6)) + bg4;
    x0[0]=xr0[0]; x0[1]=xr0[1]; x0[2]=xr0[2]; x0[3]=xr0[3];
    const float4* wr1 = (const float4*)(W + (size_t)(kb+1)*N) + nq;   w1 = *wr1;
    const float4* xr1 = (const float4*)(xT + ((size_t)(kb+1)<<6)) + bg4;
    x1[0]=xr1[0]; x1[1]=xr1[1]; x1[2]=xr1[2]; x1[3]=xr1[3];
  }
  for (int k = kb; k < ke; k += 2){
    int kp0 = (k+2 < ke) ? k+2 : k;       // clamp: redundant reload on last iter
    int kp1 = (k+3 < ke) ? k+3 : k;
    float4 wn0, wn1, xn0[4], xn1[4];
    const float4* wr0 = (const float4*)(W + (size_t)kp0*N) + nq;      wn0 = *wr0;
    const float4* xr0 = (const float4*)(xT + ((size_t)kp0<<6)) + bg4;
    xn0[0]=xr0[0]; xn0[1]=xr0[1]; xn0[2]=xr0[2]; xn0[3]=xr0[3];
    fma16(acc, w0, x0);
    const float4* wr1 = (const float4*)(W + (size_t)kp1*N) + nq;      wn1 = *wr1;
    const float4* xr1 = (const float4*)(xT + ((size_t)kp1<<6)) + bg4;
    xn1[0]=xr1[0]; xn1[1]=xr1[1]; xn1[2]=xr1[2]; xn1[3]=xr1[3];
    fma16(acc, w1, x1);
    w0 = wn0; w1 = wn1;
    #pragma unroll
    for (int j=0;j<4;++j){ x0[j]=xn0[j]; x1[j]=xn1[j]; }
  }

  if (!nact) return;
  int b0 = bg*16;
  if (mode == 0){
    float* pb = outp + (size_t)(ky_base + blockIdx.y)*64*N;
    #pragma unroll
    for (int bi=0; bi<16; ++bi)
      *(float4*)(pb + (size_t)(b0+bi)*N + n0) = acc[bi];
  } else {
    float4 bv = *(const float4*)(bias + n0);
    #pragma unroll
    for (int bi=0; bi<16; ++bi){
      float vv[4] = {acc[bi].x+bv.x, acc[bi].y+bv.y, acc[bi].z+bv.z, acc[bi].w+bv.w};
      size_t ob = (size_t)(b0+bi)*VP + n0;
      #pragma unroll
      for (int c=0;c<4;++c){
        float sc = outp[ob+c];
        float v = vv[c] + ((sc==NINF) ? 0.0f : sc);
        if (n0+c == 1) v = NINF;              // UNK_ID
        outp[ob+c] = v;
      }
    }
  }
}

// sum ks partials + bias(es), optional tanh; write row-major and/or k-major transposed
__global__ void reduce_ks(const float* __restrict__ part, int ks,
                          const float* __restrict__ b1, const float* __restrict__ b2,
                          int N, int act,
                          float* __restrict__ outRM, float* __restrict__ outT){
  int nq = N >> 2;
  int i = blockIdx.x*blockDim.x + threadIdx.x;
  if (i >= 64*nq) return;
  int b = i / nq, j = i - b*nq;
  int n0 = j*4;
  float4 s = make_float4(0.f,0.f,0.f,0.f);
  for (int ky=0; ky<ks; ++ky){
    float4 p = *(const float4*)(part + ((size_t)(ky*64+b))*N + n0);
    s.x+=p.x; s.y+=p.y; s.z+=p.z; s.w+=p.w;
  }
  if (b1){ float4 v = *(const float4*)(b1+n0); s.x+=v.x; s.y+=v.y; s.z+=v.z; s.w+=v.w; }
  if (b2){ float4 v = *(const float4*)(b2+n0); s.x+=v.x; s.y+=v.y; s.z+=v.z; s.w+=v.w; }
  if (act == 1){ s.x=tanhf(s.x); s.y=tanhf(s.y); s.z=tanhf(s.z); s.w=tanhf(s.w); }
  if (outRM) *(float4*)(outRM + (size_t)b*N + n0) = s;
  if (outT){
    outT[(size_t)(n0+0)*64 + b] = s.x;
    outT[(size_t)(n0+1)*64 + b] = s.y;
    outT[(size_t)(n0+2)*64 + b] = s.z;
    outT[(size_t)(n0+3)*64 + b] = s.w;
  }
}

// ---------------- LSTM cell + h.b_enc dot; writes hT (k-major) + out_h/out_c ----------------
__global__ __launch_bounds__(1024) void lstm_kernel(
    const float* __restrict__ gates, const float* __restrict__ prev_c,
    const float* __restrict__ b_enc,
    float* __restrict__ hT, float* __restrict__ hb,
    float* __restrict__ out_h, float* __restrict__ out_c){
  int b = blockIdx.x, h = threadIdx.x;
  size_t g0 = (size_t)b*4096;
  float ig = gates[g0+h], fg = gates[g0+1024+h], gg = gates[g0+2048+h], og = gates[g0+3072+h];
  float c0 = prev_c[(size_t)b*HD + h];
  float si = 1.0f/(1.0f+expf(-ig));
  float sf = 1.0f/(1.0f+expf(-fg));
  float so = 1.0f/(1.0f+expf(-og));
  float c  = sf*c0 + si*tanhf(gg);
  float hv = so*tanhf(c);
  hT[(size_t)h*64 + b] = hv;
  out_h[(size_t)b*HD + h] = hv;
  out_c[(size_t)b*HD + h] = c;
  float p = hv * b_enc[h];
  #pragma unroll
  for (int off=32; off; off>>=1) p += __shfl_xor(p, off, 64);
  __shared__ float red[16];
  if ((h & 63) == 0) red[h>>6] = p;
  __syncthreads();
  if (h == 0){
    float s = 0.f;
    #pragma unroll
    for (int i=0; i<16; ++i) s += red[i];
    hb[b] = s;
  }
}

// energy[b,s] = hW[b].enc[b,s] + hb[b], masked
__global__ void energy_kernel(const float* __restrict__ hW, const float* __restrict__ enc,
                              const float* __restrict__ hb, const int* __restrict__ mask,
                              float* __restrict__ energy){
  int b  = blockIdx.x / 100;
  int s0 = (blockIdx.x % 100)*4;
  __shared__ float sh[HD];
  for (int i=threadIdx.x; i<HD; i+=256) sh[i] = hW[(size_t)b*HD + i];
  __syncthreads();
  int wid = threadIdx.x >> 6, l = threadIdx.x & 63;
  int s = s0 + wid;
  const float* ep = enc + ((size_t)b*SEQ + s)*HD;
  float d = 0.f;
  #pragma unroll
  for (int it=0; it<4; ++it){
    int hh = it*256 + l*4;
    float4 e = *(const float4*)(ep + hh);
    float4 a = *(const float4*)(sh + hh);
    d += a.x*e.x + a.y*e.y + a.z*e.z + a.w*e.w;
  }
  #pragma unroll
  for (int off=32; off; off>>=1) d += __shfl_xor(d, off, 64);
  if (l == 0){
    float v = d + hb[b];
    if (mask[b*SEQ + s]) v = NINF;
    energy[b*SEQ + s] = v;
  }
}

__global__ void softmax_kernel(const float* __restrict__ energy, float* __restrict__ attn){
  int b = blockIdx.x, t = threadIdx.x;      // 256 threads, S=400
  __shared__ float red[256];
  float e0 = energy[b*SEQ + t];
  float e1 = (t+256 < SEQ) ? energy[b*SEQ + t + 256] : NINF;
  red[t] = fmaxf(e0, e1);
  __syncthreads();
  for (int o=128; o; o>>=1){ if (t < o) red[t] = fmaxf(red[t], red[t+o]); __syncthreads(); }
  float m = red[0];
  __syncthreads();
  float x0 = expf(e0 - m);
  float x1 = (t+256 < SEQ) ? expf(e1 - m) : 0.0f;
  red[t] = x0 + x1;
  __syncthreads();
  for (int o=128; o; o>>=1){ if (t < o) red[t] += red[t+o]; __syncthreads(); }
  float inv = 1.0f / red[0];
  attn[b*SEQ + t] = x0*inv;
  if (t+256 < SEQ) attn[b*SEQ + t + 256] = x1*inv;
}

__global__ void scatter_kernel(const float* __restrict__ energy, const int* __restrict__ ext_x,
                               float* __restrict__ out){
  int i = blockIdx.x*blockDim.x + threadIdx.x;
  if (i >= 64*SEQ) return;
  int b = i / SEQ;
  atomicMaxF(out + (size_t)b*VP + ext_x[i], energy[i]);
}

__global__ void oov_kernel(float* __restrict__ out){
  int i = blockIdx.x*blockDim.x + threadIdx.x;
  if (i >= 64*50) return;
  int b = i/50, j = i%50;
  size_t o = (size_t)b*VP + VV + j;
  float s = out[o];
  out[o] = (s == NINF) ? 0.0f : s;
}

// ---------------- launch ----------------
extern "C" void kernel_launch(void* const* d_in, const int* in_sizes, int n_in,
                              void* d_out, int out_size, void* d_ws, size_t ws_size,
                              hipStream_t stream){
  const int*   y       = (const int*)d_in[0];
  const int*   ext_x   = (const int*)d_in[1];
  const float* prev_h  = (const float*)d_in[2];   // (1,B,H)
  const float* prev_c  = (const float*)d_in[3];
  const float* prev_ctx= (const float*)d_in[4];   // (B,1,H)
  const float* enc     = (const float*)d_in[5];   // (B,S,H)
  const int*   mask    = (const int*)d_in[6];
  const float* decout  = (const float*)d_in[7];   // (B,1,E)
  const float* emb     = (const float*)d_in[8];
  const float* W_enc   = (const float*)d_in[9];
  const float* b_enc   = (const float*)d_in[10];
  const float* W_comb  = (const float*)d_in[11];
  const float* b_comb  = (const float*)d_in[12];
  const float* W_red   = (const float*)d_in[13];
  const float* b_red   = (const float*)d_in[14];
  const float* W_ih    = (const float*)d_in[15];
  const float* W_hh    = (const float*)d_in[16];
  const float* b_ih    = (const float*)d_in[17];
  const float* b_hh    = (const float*)d_in[18];
  const float* W_cat   = (const float*)d_in[19];
  const float* b_cat   = (const float*)d_in[20];
  const float* W_logit = (const float*)d_in[21];
  const float* b_logit = (const float*)d_in[22];

  float* ws      = (float*)d_ws;
  float* gpart   = ws;                    // 2,097,152 (gemm partials; aliases wsum partial)
  float* WencT   = ws + 2097152;          // 1,048,576
  float* xT_comb = ws + 3145728;          // 1624*64 = 103,936
  float* xT_red  = ws + 3249664;          // 1324*64 = 84,736
  float* xT_gx   = ws + 3334400;          // 300*64  = 19,200
  float* hT0     = ws + 3353600;          // 65,536 (prev_h^T)
  float* pooledT = ws + 3419136;          // 65,536
  float* gates   = ws + 3484672;          // 262,144
  float* hb      = ws + 3746816;          // 64
  float* xT_cat  = ws + 3746880;          // 2048*64 = 131,072 (rows 0..1023 = h^T)
  float* hWb     = ws + 3877952;          // 65,536
  float* energy  = ws + 3943488;          // 25,600
  float* attn    = ws + 3969088;          // 25,600
  float* ctxT    = ws + 3994688;          // 65,536
  float* xT_log  = ws + 4060224;          // 65,536   (end: 4,125,760 floats = 16.5 MB)

  float* out     = (float*)d_out;
  float* out_h   = out + 3203200;
  float* out_c   = out_h + 65536;
  float* out_ctx = out_c + 65536;

  // scat staging: logit region := -INF
  fill_ninf<<<3129,256,0,stream>>>((float4*)out, 800800);
  // pooled encoder mean (pre-W_enc), written k-major
  wsum_partial<<<512,256,0,stream>>>(enc, nullptr, gpart);
  wsum_reduce<<<256,256,0,stream>>>(gpart, pooledT, 1.0f/SEQ, 1);
  transpose1024<<<dim3(32,32),dim3(32,8),0,stream>>>(W_enc, WencT);
  // k-major operand builds (tiny)
  build_xt<<<75, dim3(64,4),0,stream>>>(emb,      300,  y,       xT_comb);            // rows 0..299
  build_xt<<<75, dim3(64,4),0,stream>>>(decout,   300,  nullptr, xT_comb + 1324*64);  // rows 1324..1623
  build_xt<<<256,dim3(64,4),0,stream>>>(prev_ctx, 1024, nullptr, xT_red  + 300*64);   // rows 300..1323
  build_xt<<<256,dim3(64,4),0,stream>>>(prev_h,   1024, nullptr, hT0);

  // enc_pooled = pooledT^T @ W_enc + b_enc  -> xT_comb rows 300..1323
  gemm_v2<<<dim3(8,8),128,0,stream>>>(pooledT, W_enc, nullptr, gpart, 1024,1024,128,0,0);
  reduce_ks<<<64,256,0,stream>>>(gpart, 8, b_enc, nullptr, 1024, 0, nullptr, xT_comb + 300*64);
  // combined = xT_comb^T @ W_comb + b_comb -> xT_red rows 0..299
  gemm_v2<<<dim3(3,8),128,0,stream>>>(xT_comb, W_comb, nullptr, gpart, 1624,300,204,0,0);
  reduce_ks<<<19,256,0,stream>>>(gpart, 8, b_comb, nullptr, 300, 0, nullptr, xT_red);
  // x = xT_red^T @ W_red + b_red -> xT_gx
  gemm_v2<<<dim3(3,8),128,0,stream>>>(xT_red, W_red, nullptr, gpart, 1324,300,166,0,0);
  reduce_ks<<<19,256,0,stream>>>(gpart, 8, b_red, nullptr, 300, 0, nullptr, xT_gx);
  // gates = x@W_ih + h0@W_hh + b_ih + b_hh (two gemms into one partial set)
  gemm_v2<<<dim3(32,2),128,0,stream>>>(xT_gx, W_ih, nullptr, gpart, 300, 4096,150,0,0);
  gemm_v2<<<dim3(32,6),128,0,stream>>>(hT0,   W_hh, nullptr, gpart, 1024,4096,172,2,0);
  reduce_ks<<<256,256,0,stream>>>(gpart, 8, b_ih, b_hh, 4096, 0, gates, nullptr);
  lstm_kernel<<<64,1024,0,stream>>>(gates, prev_c, b_enc, xT_cat, hb, out_h, out_c);
  // hW = h @ W_enc^T
  gemm_v2<<<dim3(8,8),128,0,stream>>>(xT_cat, WencT, nullptr, gpart, 1024,1024,128,0,0);
  reduce_ks<<<64,256,0,stream>>>(gpart, 8, nullptr, nullptr, 1024, 0, hWb, nullptr);
  energy_kernel<<<6400,256,0,stream>>>(hWb, enc, hb, mask, energy);
  softmax_kernel<<<64,256,0,stream>>>(energy, attn);
  scatter_kernel<<<100,256,0,stream>>>(energy, ext_x, out);
  oov_kernel<<<13,256,0,stream>>>(out);
  // context = (attn-weighted enc sum) @ W_enc + b_enc -> out_ctx + xT_cat rows 1024..2047
  wsum_partial<<<512,256,0,stream>>>(enc, attn, gpart);
  wsum_reduce<<<256,256,0,stream>>>(gpart, ctxT, 1.0f, 1);
  gemm_v2<<<dim3(8,8),128,0,stream>>>(ctxT, W_enc, nullptr, gpart, 1024,1024,128,0,0);
  reduce_ks<<<64,256,0,stream>>>(gpart, 8, b_enc, nullptr, 1024, 0, out_ctx, xT_cat + 1024*64);
  // logit_in = tanh([h, context] @ W_cat + b_cat) -> xT_log
  gemm_v2<<<dim3(8,8),128,0,stream>>>(xT_cat, W_cat, nullptr, gpart, 2048,1024,256,0,0);
  reduce_ks<<<64,256,0,stream>>>(gpart, 8, b_cat, nullptr, 1024, 1, nullptr, xT_log);
  // out_logit = logit_in @ W_logit + b_logit (+scat merge, UNK) — direct, no ksplit
  gemm_v2<<<dim3(391,1),128,0,stream>>>(xT_log, W_logit, b_logit, out, 1024,50000,1024,0,2);
}